// Round 13
// baseline (142.882 us; speedup 1.0000x reference)
//
#include <hip/hip_runtime.h>
#include <math.h>

#define SIG_L 128000
#define NBATCH 64
#define NROWS 257
#define HOP 128
#define NUMF 999
#define NFRM 30
#define NWIN 969
#define NB_MAX 16
#define FBINS 160          // kmap entries (>= 144 used bins)
#define TILES 9            // M = 288 rows = 144 bins x (re,im)
#define KSTEPS 16
#define FPB 64             // frames per block (one column)
#define NTC 16             // ceil(999/64)
#define AKB 18432          // bytes per A kk-chunk (9 tiles x 2 planes x 1024B)
#define BETA_F 6.623413251903491f  // 1 + 10^(15/20)

typedef __attribute__((ext_vector_type(8))) short short8;
typedef __attribute__((ext_vector_type(16))) float f32x16;
typedef unsigned short ushort_t;

// RNE split of fp32 into bf16 hi + bf16 lo (hi RNE; rem = v - hi exact in fp32)
__device__ inline ushort_t bf_hi_rne(float v, float* rem) {
    unsigned u = __float_as_uint(v);
    unsigned hr = (u + 0x7FFFu + ((u >> 16) & 1u)) & 0xFFFF0000u;
    *rem = v - __uint_as_float(hr);
    return (ushort_t)(hr >> 16);
}
__device__ inline ushort_t bf_rne(float v) {
    unsigned u = __float_as_uint(v);
    return (ushort_t)((u + 0x7FFFu + ((u >> 16) & 1u)) >> 16);
}

__device__ inline void gll16(const void* g, void* l) {
    __builtin_amdgcn_global_load_lds(
        (const __attribute__((address_space(1))) unsigned int*)g,
        (__attribute__((address_space(3))) unsigned int*)l, 16, 0, 0);
}

// ---------- K0: octmat scan -> hdr[32+f] = band id of bin f (or -1) ----------
__global__ void k_scan(const float* __restrict__ oct, int NB, int* __restrict__ hdr) {
    __shared__ int smin[16], smax[16];
    int tid = threadIdx.x;
    if (tid < NB) { smin[tid] = 0x7fffffff; smax[tid] = -1; }
    __syncthreads();
    for (int idx = tid; idx < NB * NROWS; idx += blockDim.x) {
        int k = idx / NROWS, f = idx % NROWS;
        if (oct[idx] != 0.0f) { atomicMin(&smin[k], f); atomicMax(&smax[k], f); }
    }
    __syncthreads();
    if (tid < FBINS) {
        int kid = -1;
        for (int k = 0; k < NB; ++k)
            if (smax[k] >= 0 && tid >= smin[k] && tid <= smax[k]) kid = k;
        hdr[32 + tid] = kid;
    }
}

// ---------- K0b: weight pack, fragment order, kk-chunked ----------
// wpack[((kk*9 + t)*2 + p)*512 + l*8 + e]  (shorts); p: 0=hi 1=lo
// A-frag: lane l holds A[row32 = l&31][k = kk*16 + (l>>5)*8 + e]
// row32 = 2m+part -> bin = t*16 + m, part: 0=re 1=im
__global__ void k_prep(const float* __restrict__ fftmat, ushort_t* __restrict__ wpack) {
    for (int u = 0; u < 2; ++u) {
        int idx = blockIdx.x * 512 + u * 256 + threadIdx.x;   // < 147456
        int e = idx & 7, l = (idx >> 3) & 63, p = (idx >> 9) & 1;
        int tt = (idx >> 10) % TILES, kk = (idx >> 10) / TILES;
        int row32 = l & 31, kq = l >> 5;
        int bin = tt * 16 + (row32 >> 1);
        int part = row32 & 1;
        int k = kk * 16 + kq * 8 + e;
        float v = fftmat[(size_t)(part ? (NROWS + bin) : bin) * 512 + 128 + k];
        float rem; ushort_t hb = bf_hi_rne(v, &rem);
        wpack[idx] = p ? bf_rne(rem) : hb;
    }
}

// ---------- K1: MFMA STFT energies + band reduce (m97 structure) ----------
// A: LDS double-buffer via global_load_lds (18 KB/kk, linear both sides),
//    shared by all waves -> A-frags never touch the register file.
// B: full 16-kk staged once, single bf16 plane (2-term numerics, r12-proven).
// 384 thr = 6 waves = 3 M-groups (MT=3 uniform) x 2 frame-halves.
// acc = 48 AGPR/wave, ~110 unified regs, LDS 74 KB -> 2 blocks/CU, 3 waves/SIMD.
// grid (NTC, NBATCH, 2). Stores band ENERGIES (sqrt in k_corr).
__global__ __launch_bounds__(384, 3) void k_stft(
    const float* __restrict__ targ, const float* __restrict__ pred,
    const ushort_t* __restrict__ wpack, const int* __restrict__ hdr,
    float* __restrict__ xbuf, float* __restrict__ ybuf, int NB) {
    __shared__ __align__(16) char smem[2 * AKB + 32768 + 4096 + 640];
    ushort_t* As   = (ushort_t*)smem;                      // [2][9216] shorts
    ushort_t* Bs   = (ushort_t*)(smem + 2 * AKB);          // [16][2][64][8] shorts
    float*    bacc = (float*)(smem + 2 * AKB + 32768);     // [NB_MAX][FPB]
    int*      kmapS= (int*)(smem + 2 * AKB + 32768 + 4096);

    const int tid = threadIdx.x;
    const int lane = tid & 63;
    const int wv = __builtin_amdgcn_readfirstlane(tid >> 6);  // 0..5
    const int mg = wv >> 1;             // M-group: tiles [3mg, 3mg+3)
    const int fh = wv & 1;              // frame-half (one 32-frame bt)
    const int tbase = mg * 3;
    const int b = blockIdx.y, z = blockIdx.z;
    const int t0 = blockIdx.x * FPB;
    const float* __restrict__ sig = z ? pred : targ;
    float* __restrict__ out = z ? ybuf : xbuf;
    const size_t boff = (size_t)b * SIG_L;

    for (int i = tid; i < NB_MAX * FPB; i += 384) bacc[i] = 0.0f;
    for (int i = tid; i < FBINS; i += 384) kmapS[i] = hdr[32 + i];

    // ---- B stage: 2048 short8 units, coalesced 32B loads per thread ----
    for (int i = tid; i < 2048; i += 384) {
        const int fl = i >> 5, q8 = i & 31;       // q8 = 8-sample group in frame
        const int kk = q8 >> 1, kq = q8 & 1;
        float4 x0 = {0,0,0,0}, x1 = {0,0,0,0};
        if (t0 + fl < NUMF) {
            const float* p = sig + boff + (size_t)(t0 + fl) * HOP + q8 * 8;
            x0 = *(const float4*)(p); x1 = *(const float4*)(p + 4);
        }
        short8 v;
        v[0] = (short)bf_rne(x0.x); v[1] = (short)bf_rne(x0.y);
        v[2] = (short)bf_rne(x0.z); v[3] = (short)bf_rne(x0.w);
        v[4] = (short)bf_rne(x1.x); v[5] = (short)bf_rne(x1.y);
        v[6] = (short)bf_rne(x1.z); v[7] = (short)bf_rne(x1.w);
        *(short8*)&Bs[((kk * 2 + kq) * 64 + fl) * 8] = v;
    }
    // ---- A stage kk=0 into As[0] (wave-uniform LDS base + lane*16) ----
    {
        const char* gsrc = (const char*)wpack;
        for (int j = wv; j < 18; j += 6)
            gll16(gsrc + j * 1024 + lane * 16, smem + j * 1024);
    }
    __syncthreads();

    f32x16 acc0, acc1, acc2;
#pragma unroll
    for (int e = 0; e < 16; ++e) { acc0[e] = 0.0f; acc1[e] = 0.0f; acc2[e] = 0.0f; }

    const int jloc = lane & 31, kq = lane >> 5;
    const int srow = fh * 32 + jloc;    // this lane's frame within the 64-col

    int cur = 0;
#pragma unroll 1
    for (int kk = 0; kk < KSTEPS; ++kk) {
        // issue next A chunk (async; drained by this kk's barrier)
        if (kk < KSTEPS - 1) {
            const char* gsrc = (const char*)wpack + (size_t)(kk + 1) * AKB;
            char* ldst = smem + (cur ^ 1) * AKB;
            for (int j = wv; j < 18; j += 6)
                gll16(gsrc + j * 1024 + lane * 16, ldst + j * 1024);
        }
        // compute from As[cur], Bs[kk]
        short8 S = *(const short8*)&Bs[((kk * 2 + kq) * 64 + srow) * 8];
        const ushort_t* ab = As + cur * (AKB / 2) + tbase * 1024 + lane * 8;
        short8 Ah0 = *(const short8*)(ab);
        short8 Al0 = *(const short8*)(ab + 512);
        short8 Ah1 = *(const short8*)(ab + 1024);
        short8 Al1 = *(const short8*)(ab + 1536);
        short8 Ah2 = *(const short8*)(ab + 2048);
        short8 Al2 = *(const short8*)(ab + 2560);
        __builtin_amdgcn_s_setprio(1);
        acc0 = __builtin_amdgcn_mfma_f32_32x32x16_bf16(Ah0, S, acc0, 0, 0, 0);
        acc1 = __builtin_amdgcn_mfma_f32_32x32x16_bf16(Ah1, S, acc1, 0, 0, 0);
        acc2 = __builtin_amdgcn_mfma_f32_32x32x16_bf16(Ah2, S, acc2, 0, 0, 0);
        acc0 = __builtin_amdgcn_mfma_f32_32x32x16_bf16(Al0, S, acc0, 0, 0, 0);
        acc1 = __builtin_amdgcn_mfma_f32_32x32x16_bf16(Al1, S, acc1, 0, 0, 0);
        acc2 = __builtin_amdgcn_mfma_f32_32x32x16_bf16(Al2, S, acc2, 0, 0, 0);
        __builtin_amdgcn_s_setprio(0);
        __syncthreads();                 // As[cur^1] staged; As[cur] free
        cur ^= 1;
    }

    // ---- epilogue: energies -> band accumulate -> global ----
    {
        const f32x16* accs[3] = {&acc0, &acc1, &acc2};
#pragma unroll
        for (int g = 0; g < 3; ++g) {
            const f32x16 a = *accs[g];
            float run = 0.0f; int runk = -1;
#pragma unroll
            for (int rr = 0; rr < 8; ++rr) {
                const int m = (rr & 1) + 4 * (rr >> 1) + 2 * kq;
                const int kid = kmapS[(tbase + g) * 16 + m];
                const float vr = a[rr * 2], vi = a[rr * 2 + 1];
                const float e = vr * vr + vi * vi;
                if (kid != runk) {
                    if (runk >= 0) atomicAdd(&bacc[runk * FPB + srow], run);
                    run = 0.0f; runk = kid;
                }
                if (kid >= 0) run += e;
            }
            if (runk >= 0) atomicAdd(&bacc[runk * FPB + srow], run);
        }
    }
    __syncthreads();
    for (int idx = tid; idx < NB * FPB; idx += 384) {
        int k = idx >> 6, t = idx & (FPB - 1);
        int tg = t0 + t;
        if (tg < NUMF)
            out[((size_t)b * NB + k) * NUMF + tg] = bacc[k * FPB + t];
    }
}

// ---------- K2: sliding-window correlations (reads energies, applies sqrt) ----------
__global__ __launch_bounds__(256) void k_corr(const float* __restrict__ xbuf,
                                              const float* __restrict__ ybuf,
                                              int NB, double* __restrict__ partials) {
    const int k = blockIdx.x, b = blockIdx.y;
    const long roff = ((long)b * NB + k) * NUMF;
    __shared__ float xl[NUMF], yl[NUMF];
    __shared__ double red[256];
    const int tid = threadIdx.x;
    for (int i = tid; i < NUMF; i += 256) {
        xl[i] = sqrtf(xbuf[roff + i]);
        yl[i] = sqrtf(ybuf[roff + i]);
    }
    __syncthreads();
    double loc = 0.0;
    for (int w = tid; w < NWIN; w += 256) {
        float sx = 0, sxx = 0, syy = 0;
        for (int i = 0; i < NFRM; ++i) {
            float xv = xl[w + i], yv = yl[w + i];
            sx += xv; sxx += xv * xv; syy += yv * yv;
        }
        float alpha = sqrtf(sxx / (syy + 1e-7f));
        float sy = 0;
        for (int i = 0; i < NFRM; ++i)
            sy += fminf(alpha * yl[w + i], BETA_F * xl[w + i]);
        float mx = sx * (1.0f / NFRM), my = sy * (1.0f / NFRM);
        float cxx = 0, cyy = 0, cxy = 0;
        for (int i = 0; i < NFRM; ++i) {
            float dx = xl[w + i] - mx;
            float dy = fminf(alpha * yl[w + i], BETA_F * xl[w + i]) - my;
            cxx += dx * dx; cyy += dy * dy; cxy += dx * dy;
        }
        loc += (double)cxy / sqrt((double)cxx * (double)cyy);
    }
    red[tid] = loc;
    __syncthreads();
    for (int s = 128; s > 0; s >>= 1) {
        if (tid < s) red[tid] += red[tid + s];
        __syncthreads();
    }
    if (tid == 0) partials[b * NB + k] = red[0];
}

// ---------- K3: final deterministic reduction ----------
__global__ void k_final(const double* __restrict__ partials, int NB, float* __restrict__ out) {
    __shared__ double red[256];
    const int tid = threadIdx.x;
    const int n = NBATCH * NB;
    double s = 0.0;
    for (int i = tid; i < n; i += 256) s += partials[i];
    red[tid] = s;
    __syncthreads();
    for (int st = 128; st > 0; st >>= 1) {
        if (tid < st) red[tid] += red[tid + st];
        __syncthreads();
    }
    if (tid == 0) out[0] = (float)(-red[0] / ((double)NBATCH * NB * NWIN));
}

extern "C" void kernel_launch(void* const* d_in, const int* in_sizes, int n_in,
                              void* d_out, int out_size, void* d_ws, size_t ws_size,
                              hipStream_t stream) {
    const float* pred   = (const float*)d_in[0];
    const float* targ   = (const float*)d_in[1];
    const float* fftmat = (const float*)d_in[3];
    const float* oct    = (const float*)d_in[4];
    const int NB = in_sizes[4] / NROWS;   // 15

    char* ws = (char*)d_ws;
    int*      hdr   = (int*)ws;                          // 1 KB
    ushort_t* wpack = (ushort_t*)(ws + 1024);            // 147456 shorts = 294912 B
    size_t o1 = 1024 + (size_t)KSTEPS * TILES * 2 * 512 * 2;
    size_t xsz = (size_t)NBATCH * NB_MAX * NUMF * 4;
    float*  xbuf = (float*)(ws + o1);
    float*  ybuf = (float*)(ws + o1 + xsz);
    double* partials = (double*)(ws + o1 + 2 * xsz);

    hipLaunchKernelGGL(k_scan, dim3(1), dim3(256), 0, stream, oct, NB, hdr);
    hipLaunchKernelGGL(k_prep, dim3(288), dim3(256), 0, stream, fftmat, wpack);
    hipLaunchKernelGGL(k_stft, dim3(NTC, NBATCH, 2), dim3(384), 0, stream,
                       targ, pred, wpack, hdr, xbuf, ybuf, NB);
    hipLaunchKernelGGL(k_corr, dim3(NB, NBATCH), dim3(256), 0, stream, xbuf, ybuf, NB, partials);
    hipLaunchKernelGGL(k_final, dim3(1), dim3(256), 0, stream, partials, NB, (float*)d_out);
}

// Round 14
// 112.432 us; speedup vs baseline: 1.2708x; 1.2708x over previous
//
#include <hip/hip_runtime.h>
#include <math.h>

#define SIG_L 128000
#define NBATCH 64
#define NROWS 257
#define HOP 128
#define NUMF 999
#define NFRM 30
#define NWIN 969
#define NB_MAX 16
#define FBINS 160          // kmap entries (>= 144 used bins)
#define TILES 9            // M = 288 rows = 144 bins x (re,im)
#define KSTEPS 16
#define FPB2 128           // frames per block (two 64-columns)
#define NTC2 8             // ceil(999/128)
#define AKB 18432          // bytes per A kk-chunk (9 tiles x 2 planes x 1024B)
#define BETA_F 6.623413251903491f  // 1 + 10^(15/20)

typedef __attribute__((ext_vector_type(8))) short short8;
typedef __attribute__((ext_vector_type(16))) float f32x16;
typedef unsigned short ushort_t;

// RNE split of fp32 into bf16 hi + bf16 lo (hi RNE; rem = v - hi exact in fp32)
__device__ inline ushort_t bf_hi_rne(float v, float* rem) {
    unsigned u = __float_as_uint(v);
    unsigned hr = (u + 0x7FFFu + ((u >> 16) & 1u)) & 0xFFFF0000u;
    *rem = v - __uint_as_float(hr);
    return (ushort_t)(hr >> 16);
}
__device__ inline ushort_t bf_rne(float v) {
    unsigned u = __float_as_uint(v);
    return (ushort_t)((u + 0x7FFFu + ((u >> 16) & 1u)) >> 16);
}

__device__ inline void gll16(const void* g, void* l) {
    __builtin_amdgcn_global_load_lds(
        (const __attribute__((address_space(1))) unsigned int*)g,
        (__attribute__((address_space(3))) unsigned int*)l, 16, 0, 0);
}

// ---------- K0: octmat scan -> hdr[32+f] = band id of bin f (or -1) ----------
__global__ void k_scan(const float* __restrict__ oct, int NB, int* __restrict__ hdr) {
    __shared__ int smin[16], smax[16];
    int tid = threadIdx.x;
    if (tid < NB) { smin[tid] = 0x7fffffff; smax[tid] = -1; }
    __syncthreads();
    for (int idx = tid; idx < NB * NROWS; idx += blockDim.x) {
        int k = idx / NROWS, f = idx % NROWS;
        if (oct[idx] != 0.0f) { atomicMin(&smin[k], f); atomicMax(&smax[k], f); }
    }
    __syncthreads();
    if (tid < FBINS) {
        int kid = -1;
        for (int k = 0; k < NB; ++k)
            if (smax[k] >= 0 && tid >= smin[k] && tid <= smax[k]) kid = k;
        hdr[32 + tid] = kid;
    }
}

// ---------- K0b: weight pack, fragment order, kk-chunked ----------
// wpack[((kk*9 + t)*2 + p)*512 + l*8 + e]  (shorts); p: 0=hi 1=lo
// A-frag: lane l holds A[row32 = l&31][k = kk*16 + (l>>5)*8 + e]
// row32 = 2m+part -> bin = t*16 + m, part: 0=re 1=im
__global__ void k_prep(const float* __restrict__ fftmat, ushort_t* __restrict__ wpack) {
    for (int u = 0; u < 2; ++u) {
        int idx = blockIdx.x * 512 + u * 256 + threadIdx.x;   // < 147456
        int e = idx & 7, l = (idx >> 3) & 63, p = (idx >> 9) & 1;
        int tt = (idx >> 10) % TILES, kk = (idx >> 10) / TILES;
        int row32 = l & 31, kq = l >> 5;
        int bin = tt * 16 + (row32 >> 1);
        int part = row32 & 1;
        int k = kk * 16 + kq * 8 + e;
        float v = fftmat[(size_t)(part ? (NROWS + bin) : bin) * 512 + 128 + k];
        float rem; ushort_t hb = bf_hi_rne(v, &rem);
        wpack[idx] = p ? bf_rne(rem) : hb;
    }
}

// ---------- K1: MFMA STFT energies + band reduce (amortized 128-frame block) ----------
// 768 thr = 12 waves = 3 M-groups x 2 cols x 2 bt; acc = 48 AGPR/wave.
// LDS: A dbuf 36 KB (global_load_lds) + full B 64 KB bf16 + bacc -> 111 KB, 1 blk/CU,
// 3 waves/SIMD. Each 18 KB A-stage feeds 1152 MFMA (2x r13). 2-term numerics (r12).
// grid (NTC2, NBATCH, 2). Stores band ENERGIES (sqrt in k_corr).
__global__ __launch_bounds__(768, 3) void k_stft(
    const float* __restrict__ targ, const float* __restrict__ pred,
    const ushort_t* __restrict__ wpack, const int* __restrict__ hdr,
    float* __restrict__ xbuf, float* __restrict__ ybuf, int NB) {
    __shared__ __align__(16) char smem[2 * AKB + 65536 + 8192 + 640];
    ushort_t* As    = (ushort_t*)smem;                       // [2][9216] shorts
    ushort_t* Bs    = (ushort_t*)(smem + 2 * AKB);           // [16][2][128][8] shorts
    float*    bacc  = (float*)(smem + 2 * AKB + 65536);      // [NB_MAX][FPB2]
    int*      kmapS = (int*)(smem + 2 * AKB + 65536 + 8192);

    const int tid = threadIdx.x;
    const int lane = tid & 63;
    const int wv = __builtin_amdgcn_readfirstlane(tid >> 6); // 0..11
    const int mg  = wv >> 2;            // M-group: tiles [3mg, 3mg+3)
    const int col = (wv >> 1) & 1;      // which 64-frame column
    const int bt  = wv & 1;             // 32-frame sub-tile
    const int tbase = mg * 3;
    const int b = blockIdx.y, z = blockIdx.z;
    const int t0 = blockIdx.x * FPB2;
    const float* __restrict__ sig = z ? pred : targ;
    float* __restrict__ out = z ? ybuf : xbuf;
    const size_t boff = (size_t)b * SIG_L;

    for (int i = tid; i < NB_MAX * FPB2; i += 768) bacc[i] = 0.0f;
    for (int i = tid; i < FBINS; i += 768) kmapS[i] = hdr[32 + i];

    // ---- B stage: 4096 short8 units (fl 0..127, q8 0..31), 32B loads ----
    for (int i = tid; i < 4096; i += 768) {
        const int fl = i >> 5, q8 = i & 31;
        const int kk = q8 >> 1, kq = q8 & 1;
        float4 x0 = {0,0,0,0}, x1 = {0,0,0,0};
        if (t0 + fl < NUMF) {
            const float* p = sig + boff + (size_t)(t0 + fl) * HOP + q8 * 8;
            x0 = *(const float4*)(p); x1 = *(const float4*)(p + 4);
        }
        short8 v;
        v[0] = (short)bf_rne(x0.x); v[1] = (short)bf_rne(x0.y);
        v[2] = (short)bf_rne(x0.z); v[3] = (short)bf_rne(x0.w);
        v[4] = (short)bf_rne(x1.x); v[5] = (short)bf_rne(x1.y);
        v[6] = (short)bf_rne(x1.z); v[7] = (short)bf_rne(x1.w);
        *(short8*)&Bs[((kk * 2 + kq) * FPB2 + fl) * 8] = v;
    }
    // ---- A stage kk=0 into As[0] ----
    {
        const char* gsrc = (const char*)wpack;
        for (int j = wv; j < 18; j += 12)
            gll16(gsrc + j * 1024 + lane * 16, smem + j * 1024);
    }
    __syncthreads();

    f32x16 acc0, acc1, acc2;
#pragma unroll
    for (int e = 0; e < 16; ++e) { acc0[e] = 0.0f; acc1[e] = 0.0f; acc2[e] = 0.0f; }

    const int jloc = lane & 31, kq = lane >> 5;
    const int fl = col * 64 + bt * 32 + jloc;   // this lane's frame (block-local)

    int cur = 0;
#pragma unroll 1
    for (int kk = 0; kk < KSTEPS; ++kk) {
        // issue next A chunk (async; drained by this kk's barrier)
        if (kk < KSTEPS - 1) {
            const char* gsrc = (const char*)wpack + (size_t)(kk + 1) * AKB;
            char* ldst = smem + (cur ^ 1) * AKB;
            for (int j = wv; j < 18; j += 12)
                gll16(gsrc + j * 1024 + lane * 16, ldst + j * 1024);
        }
        // compute from As[cur], Bs[kk]
        short8 S = *(const short8*)&Bs[((kk * 2 + kq) * FPB2 + fl) * 8];
        const ushort_t* ab = As + cur * (AKB / 2) + tbase * 1024 + lane * 8;
        short8 Ah0 = *(const short8*)(ab);
        short8 Al0 = *(const short8*)(ab + 512);
        short8 Ah1 = *(const short8*)(ab + 1024);
        short8 Al1 = *(const short8*)(ab + 1536);
        short8 Ah2 = *(const short8*)(ab + 2048);
        short8 Al2 = *(const short8*)(ab + 2560);
        __builtin_amdgcn_s_setprio(1);
        acc0 = __builtin_amdgcn_mfma_f32_32x32x16_bf16(Ah0, S, acc0, 0, 0, 0);
        acc1 = __builtin_amdgcn_mfma_f32_32x32x16_bf16(Ah1, S, acc1, 0, 0, 0);
        acc2 = __builtin_amdgcn_mfma_f32_32x32x16_bf16(Ah2, S, acc2, 0, 0, 0);
        acc0 = __builtin_amdgcn_mfma_f32_32x32x16_bf16(Al0, S, acc0, 0, 0, 0);
        acc1 = __builtin_amdgcn_mfma_f32_32x32x16_bf16(Al1, S, acc1, 0, 0, 0);
        acc2 = __builtin_amdgcn_mfma_f32_32x32x16_bf16(Al2, S, acc2, 0, 0, 0);
        __builtin_amdgcn_s_setprio(0);
        __syncthreads();                 // As[cur^1] staged; As[cur] free
        cur ^= 1;
    }

    // ---- epilogue: energies -> band accumulate -> global ----
    {
        const f32x16* accs[3] = {&acc0, &acc1, &acc2};
#pragma unroll
        for (int g = 0; g < 3; ++g) {
            const f32x16 a = *accs[g];
            float run = 0.0f; int runk = -1;
#pragma unroll
            for (int rr = 0; rr < 8; ++rr) {
                const int m = (rr & 1) + 4 * (rr >> 1) + 2 * kq;
                const int kid = kmapS[(tbase + g) * 16 + m];
                const float vr = a[rr * 2], vi = a[rr * 2 + 1];
                const float e = vr * vr + vi * vi;
                if (kid != runk) {
                    if (runk >= 0) atomicAdd(&bacc[runk * FPB2 + fl], run);
                    run = 0.0f; runk = kid;
                }
                if (kid >= 0) run += e;
            }
            if (runk >= 0) atomicAdd(&bacc[runk * FPB2 + fl], run);
        }
    }
    __syncthreads();
    for (int idx = tid; idx < NB * FPB2; idx += 768) {
        int k = idx >> 7, t = idx & (FPB2 - 1);
        int tg = t0 + t;
        if (tg < NUMF)
            out[((size_t)b * NB + k) * NUMF + tg] = bacc[k * FPB2 + t];
    }
}

// ---------- K2: sliding-window correlations (reads energies, applies sqrt) ----------
__global__ __launch_bounds__(256) void k_corr(const float* __restrict__ xbuf,
                                              const float* __restrict__ ybuf,
                                              int NB, double* __restrict__ partials) {
    const int k = blockIdx.x, b = blockIdx.y;
    const long roff = ((long)b * NB + k) * NUMF;
    __shared__ float xl[NUMF], yl[NUMF];
    __shared__ double red[256];
    const int tid = threadIdx.x;
    for (int i = tid; i < NUMF; i += 256) {
        xl[i] = sqrtf(xbuf[roff + i]);
        yl[i] = sqrtf(ybuf[roff + i]);
    }
    __syncthreads();
    double loc = 0.0;
    for (int w = tid; w < NWIN; w += 256) {
        float sx = 0, sxx = 0, syy = 0;
        for (int i = 0; i < NFRM; ++i) {
            float xv = xl[w + i], yv = yl[w + i];
            sx += xv; sxx += xv * xv; syy += yv * yv;
        }
        float alpha = sqrtf(sxx / (syy + 1e-7f));
        float sy = 0;
        for (int i = 0; i < NFRM; ++i)
            sy += fminf(alpha * yl[w + i], BETA_F * xl[w + i]);
        float mx = sx * (1.0f / NFRM), my = sy * (1.0f / NFRM);
        float cxx = 0, cyy = 0, cxy = 0;
        for (int i = 0; i < NFRM; ++i) {
            float dx = xl[w + i] - mx;
            float dy = fminf(alpha * yl[w + i], BETA_F * xl[w + i]) - my;
            cxx += dx * dx; cyy += dy * dy; cxy += dx * dy;
        }
        loc += (double)cxy / sqrt((double)cxx * (double)cyy);
    }
    red[tid] = loc;
    __syncthreads();
    for (int s = 128; s > 0; s >>= 1) {
        if (tid < s) red[tid] += red[tid + s];
        __syncthreads();
    }
    if (tid == 0) partials[b * NB + k] = red[0];
}

// ---------- K3: final deterministic reduction ----------
__global__ void k_final(const double* __restrict__ partials, int NB, float* __restrict__ out) {
    __shared__ double red[256];
    const int tid = threadIdx.x;
    const int n = NBATCH * NB;
    double s = 0.0;
    for (int i = tid; i < n; i += 256) s += partials[i];
    red[tid] = s;
    __syncthreads();
    for (int st = 128; st > 0; st >>= 1) {
        if (tid < st) red[tid] += red[tid + st];
        __syncthreads();
    }
    if (tid == 0) out[0] = (float)(-red[0] / ((double)NBATCH * NB * NWIN));
}

extern "C" void kernel_launch(void* const* d_in, const int* in_sizes, int n_in,
                              void* d_out, int out_size, void* d_ws, size_t ws_size,
                              hipStream_t stream) {
    const float* pred   = (const float*)d_in[0];
    const float* targ   = (const float*)d_in[1];
    const float* fftmat = (const float*)d_in[3];
    const float* oct    = (const float*)d_in[4];
    const int NB = in_sizes[4] / NROWS;   // 15

    char* ws = (char*)d_ws;
    int*      hdr   = (int*)ws;                          // 1 KB
    ushort_t* wpack = (ushort_t*)(ws + 1024);            // 147456 shorts = 294912 B
    size_t o1 = 1024 + (size_t)KSTEPS * TILES * 2 * 512 * 2;
    size_t xsz = (size_t)NBATCH * NB_MAX * NUMF * 4;
    float*  xbuf = (float*)(ws + o1);
    float*  ybuf = (float*)(ws + o1 + xsz);
    double* partials = (double*)(ws + o1 + 2 * xsz);

    hipLaunchKernelGGL(k_scan, dim3(1), dim3(256), 0, stream, oct, NB, hdr);
    hipLaunchKernelGGL(k_prep, dim3(288), dim3(256), 0, stream, fftmat, wpack);
    hipLaunchKernelGGL(k_stft, dim3(NTC2, NBATCH, 2), dim3(768), 0, stream,
                       targ, pred, wpack, hdr, xbuf, ybuf, NB);
    hipLaunchKernelGGL(k_corr, dim3(NB, NBATCH), dim3(256), 0, stream, xbuf, ybuf, NB, partials);
    hipLaunchKernelGGL(k_final, dim3(1), dim3(256), 0, stream, partials, NB, (float*)d_out);
}

// Round 15
// 103.720 us; speedup vs baseline: 1.3776x; 1.0840x over previous
//
#include <hip/hip_runtime.h>
#include <math.h>

#define SIG_L 128000
#define NBATCH 64
#define NROWS 257
#define HOP 128
#define NUMF 999
#define NFRM 30
#define NWIN 969
#define NB_MAX 16
#define FBINS 160          // kmap entries (>= 144 used bins)
#define TILES 9            // M = 288 rows = 144 bins x (re,im)
#define KSTEPS 16
#define FPBX 256           // frames per block (four 64-columns)
#define NTX 4              // ceil(999/256)
#define AKB 18432          // bytes per A kk-chunk (9 tiles x 2 planes x 1024B)
#define BCH 4112           // B 16-byte chunks: (255*128+256)/8 = 4112
#define BETA_F 6.623413251903491f  // 1 + 10^(15/20)

typedef __attribute__((ext_vector_type(8))) short short8;
typedef __attribute__((ext_vector_type(16))) float f32x16;
typedef unsigned short ushort_t;

// RNE split of fp32 into bf16 hi + bf16 lo (hi RNE; rem = v - hi exact in fp32)
__device__ inline ushort_t bf_hi_rne(float v, float* rem) {
    unsigned u = __float_as_uint(v);
    unsigned hr = (u + 0x7FFFu + ((u >> 16) & 1u)) & 0xFFFF0000u;
    *rem = v - __uint_as_float(hr);
    return (ushort_t)(hr >> 16);
}
__device__ inline ushort_t bf_rne(float v) {
    unsigned u = __float_as_uint(v);
    return (ushort_t)((u + 0x7FFFu + ((u >> 16) & 1u)) >> 16);
}

__device__ inline void gll16(const void* g, void* l) {
    __builtin_amdgcn_global_load_lds(
        (const __attribute__((address_space(1))) unsigned int*)g,
        (__attribute__((address_space(3))) unsigned int*)l, 16, 0, 0);
}

// ---------- K0: octmat scan -> hdr[32+f] = band id of bin f (or -1) ----------
__global__ void k_scan(const float* __restrict__ oct, int NB, int* __restrict__ hdr) {
    __shared__ int smin[16], smax[16];
    int tid = threadIdx.x;
    if (tid < NB) { smin[tid] = 0x7fffffff; smax[tid] = -1; }
    __syncthreads();
    for (int idx = tid; idx < NB * NROWS; idx += blockDim.x) {
        int k = idx / NROWS, f = idx % NROWS;
        if (oct[idx] != 0.0f) { atomicMin(&smin[k], f); atomicMax(&smax[k], f); }
    }
    __syncthreads();
    if (tid < FBINS) {
        int kid = -1;
        for (int k = 0; k < NB; ++k)
            if (smax[k] >= 0 && tid >= smin[k] && tid <= smax[k]) kid = k;
        hdr[32 + tid] = kid;
    }
}

// ---------- K0b: weight pack, fragment order, kk-chunked ----------
// wpack[((kk*9 + t)*2 + p)*512 + l*8 + e]  (shorts); p: 0=hi 1=lo
// A-frag: lane l holds A[row32 = l&31][k = kk*16 + (l>>5)*8 + e]
// row32 = 2m+part -> bin = t*16 + m, part: 0=re 1=im
__global__ void k_prep(const float* __restrict__ fftmat, ushort_t* __restrict__ wpack) {
    for (int u = 0; u < 2; ++u) {
        int idx = blockIdx.x * 512 + u * 256 + threadIdx.x;   // < 147456
        int e = idx & 7, l = (idx >> 3) & 63, p = (idx >> 9) & 1;
        int tt = (idx >> 10) % TILES, kk = (idx >> 10) / TILES;
        int row32 = l & 31, kq = l >> 5;
        int bin = tt * 16 + (row32 >> 1);
        int part = row32 & 1;
        int k = kk * 16 + kq * 8 + e;
        float v = fftmat[(size_t)(part ? (NROWS + bin) : bin) * 512 + 128 + k];
        float rem; ushort_t hb = bf_hi_rne(v, &rem);
        wpack[idx] = p ? bf_rne(rem) : hb;
    }
}

// ---------- K1: MFMA STFT energies + band reduce ----------
// 768 thr = 12 waves = 3 M-groups x 4 cols; wave owns 64 frames -> acc[3][2]
// (each A ds_read feeds 2 MFMAs). B = RAW signal bf16 in LDS (66 KB, frames
// overlap 2x) with byte-XOR swizzle vs 32-way fl-stride conflicts.
// A: LDS dbuf via global_load_lds, 18 KB/kk feeding 2304 MFMA. 2-term numerics.
// LDS 119.7 KB -> 1 blk/CU, 3 waves/SIMD. grid (NTX, NBATCH, 2).
__global__ __launch_bounds__(768, 3) void k_stft(
    const float* __restrict__ targ, const float* __restrict__ pred,
    const ushort_t* __restrict__ wpack, const int* __restrict__ hdr,
    float* __restrict__ xbuf, float* __restrict__ ybuf, int NB) {
    __shared__ __align__(16) char smem[2 * AKB + BCH * 16 + NB_MAX * FPBX * 4 + 640];
    ushort_t* As    = (ushort_t*)smem;                             // [2][9216] shorts
    char*     Bs    = smem + 2 * AKB;                              // raw bf16, swizzled
    float*    bacc  = (float*)(smem + 2 * AKB + BCH * 16);         // [NB_MAX][FPBX]
    int*      kmapS = (int*)(smem + 2 * AKB + BCH * 16 + NB_MAX * FPBX * 4);

    const int tid = threadIdx.x;
    const int lane = tid & 63;
    const int wv = __builtin_amdgcn_readfirstlane(tid >> 6); // 0..11
    const int mg  = wv >> 2;            // M-group: tiles [3mg, 3mg+3)
    const int col = wv & 3;             // 64-frame column
    const int tbase = mg * 3;
    const int b = blockIdx.y, z = blockIdx.z;
    const int t0 = blockIdx.x * FPBX;
    const float* __restrict__ sig = z ? pred : targ;
    float* __restrict__ out = z ? ybuf : xbuf;
    const size_t boff = (size_t)b * SIG_L;

    for (int i = tid; i < NB_MAX * FPBX; i += 768) bacc[i] = 0.0f;
    for (int i = tid; i < FBINS; i += 768) kmapS[i] = hdr[32 + i];

    // ---- B stage: raw signal -> bf16, XOR-swizzled 16B chunks ----
    const long sbase = (long)t0 * HOP;
    for (int c = tid; c < BCH; c += 768) {
        const long g0 = sbase + (long)c * 8;
        float v[8];
        if (g0 + 8 <= SIG_L) {
            float4 x0 = *(const float4*)(sig + boff + g0);
            float4 x1 = *(const float4*)(sig + boff + g0 + 4);
            v[0] = x0.x; v[1] = x0.y; v[2] = x0.z; v[3] = x0.w;
            v[4] = x1.x; v[5] = x1.y; v[6] = x1.z; v[7] = x1.w;
        } else {
#pragma unroll
            for (int e = 0; e < 8; ++e)
                v[e] = (g0 + e < SIG_L) ? sig[boff + g0 + e] : 0.0f;
        }
        short8 sv;
#pragma unroll
        for (int e = 0; e < 8; ++e) sv[e] = (short)bf_rne(v[e]);
        int byte = c * 16;
        byte ^= ((byte >> 8) & 0xF) << 4;
        *(short8*)(Bs + byte) = sv;
    }
    // ---- A stage kk=0 into As[0] ----
    {
        const char* gsrc = (const char*)wpack;
        for (int j = wv; j < 18; j += 12)
            gll16(gsrc + j * 1024 + lane * 16, smem + j * 1024);
    }
    __syncthreads();

    f32x16 acc[3][2];
#pragma unroll
    for (int g = 0; g < 3; ++g)
#pragma unroll
        for (int bt = 0; bt < 2; ++bt)
#pragma unroll
            for (int e = 0; e < 16; ++e) acc[g][bt][e] = 0.0f;

    const int jloc = lane & 31, kq = lane >> 5;

    int cur = 0;
#pragma unroll 1
    for (int kk = 0; kk < KSTEPS; ++kk) {
        // issue next A chunk (async; drained by this kk's barrier)
        if (kk < KSTEPS - 1) {
            const char* gsrc = (const char*)wpack + (size_t)(kk + 1) * AKB;
            char* ldst = smem + (cur ^ 1) * AKB;
            for (int j = wv; j < 18; j += 12)
                gll16(gsrc + j * 1024 + lane * 16, ldst + j * 1024);
        }
        // B fragments: frame fl's samples [kk*16 + kq*8 .. +8) from raw buffer
        short8 S[2];
#pragma unroll
        for (int bt = 0; bt < 2; ++bt) {
            const int fl = col * 64 + bt * 32 + jloc;
            int byte = fl * 256 + kk * 32 + kq * 16;
            byte ^= ((byte >> 8) & 0xF) << 4;
            S[bt] = *(const short8*)(Bs + byte);
        }
        const ushort_t* ab = As + cur * (AKB / 2) + tbase * 1024 + lane * 8;
        __builtin_amdgcn_s_setprio(1);
#pragma unroll
        for (int g = 0; g < 3; ++g) {
            short8 Ah = *(const short8*)(ab + g * 1024);
            short8 Al = *(const short8*)(ab + g * 1024 + 512);
            acc[g][0] = __builtin_amdgcn_mfma_f32_32x32x16_bf16(Ah, S[0], acc[g][0], 0, 0, 0);
            acc[g][1] = __builtin_amdgcn_mfma_f32_32x32x16_bf16(Ah, S[1], acc[g][1], 0, 0, 0);
            acc[g][0] = __builtin_amdgcn_mfma_f32_32x32x16_bf16(Al, S[0], acc[g][0], 0, 0, 0);
            acc[g][1] = __builtin_amdgcn_mfma_f32_32x32x16_bf16(Al, S[1], acc[g][1], 0, 0, 0);
        }
        __builtin_amdgcn_s_setprio(0);
        __syncthreads();                 // As[cur^1] staged; As[cur] free
        cur ^= 1;
    }

    // ---- epilogue: energies -> band accumulate -> global ----
#pragma unroll
    for (int g = 0; g < 3; ++g) {
#pragma unroll
        for (int bt = 0; bt < 2; ++bt) {
            const int fl = col * 64 + bt * 32 + jloc;
            float run = 0.0f; int runk = -1;
#pragma unroll
            for (int rr = 0; rr < 8; ++rr) {
                const int m = (rr & 1) + 4 * (rr >> 1) + 2 * kq;
                const int kid = kmapS[(tbase + g) * 16 + m];
                const float vr = acc[g][bt][rr * 2], vi = acc[g][bt][rr * 2 + 1];
                const float e = vr * vr + vi * vi;
                if (kid != runk) {
                    if (runk >= 0) atomicAdd(&bacc[runk * FPBX + fl], run);
                    run = 0.0f; runk = kid;
                }
                if (kid >= 0) run += e;
            }
            if (runk >= 0) atomicAdd(&bacc[runk * FPBX + fl], run);
        }
    }
    __syncthreads();
    for (int idx = tid; idx < NB * FPBX; idx += 768) {
        int k = idx >> 8, t = idx & (FPBX - 1);
        int tg = t0 + t;
        if (tg < NUMF)
            out[((size_t)b * NB + k) * NUMF + tg] = bacc[k * FPBX + t];
    }
}

// ---------- K2: sliding-window correlations (reads energies, applies sqrt) ----------
__global__ __launch_bounds__(256) void k_corr(const float* __restrict__ xbuf,
                                              const float* __restrict__ ybuf,
                                              int NB, double* __restrict__ partials) {
    const int k = blockIdx.x, b = blockIdx.y;
    const long roff = ((long)b * NB + k) * NUMF;
    __shared__ float xl[NUMF], yl[NUMF];
    __shared__ double red[256];
    const int tid = threadIdx.x;
    for (int i = tid; i < NUMF; i += 256) {
        xl[i] = sqrtf(xbuf[roff + i]);
        yl[i] = sqrtf(ybuf[roff + i]);
    }
    __syncthreads();
    double loc = 0.0;
    for (int w = tid; w < NWIN; w += 256) {
        float sx = 0, sxx = 0, syy = 0;
        for (int i = 0; i < NFRM; ++i) {
            float xv = xl[w + i], yv = yl[w + i];
            sx += xv; sxx += xv * xv; syy += yv * yv;
        }
        float alpha = sqrtf(sxx / (syy + 1e-7f));
        float sy = 0;
        for (int i = 0; i < NFRM; ++i)
            sy += fminf(alpha * yl[w + i], BETA_F * xl[w + i]);
        float mx = sx * (1.0f / NFRM), my = sy * (1.0f / NFRM);
        float cxx = 0, cyy = 0, cxy = 0;
        for (int i = 0; i < NFRM; ++i) {
            float dx = xl[w + i] - mx;
            float dy = fminf(alpha * yl[w + i], BETA_F * xl[w + i]) - my;
            cxx += dx * dx; cyy += dy * dy; cxy += dx * dy;
        }
        loc += (double)cxy / sqrt((double)cxx * (double)cyy);
    }
    red[tid] = loc;
    __syncthreads();
    for (int s = 128; s > 0; s >>= 1) {
        if (tid < s) red[tid] += red[tid + s];
        __syncthreads();
    }
    if (tid == 0) partials[b * NB + k] = red[0];
}

// ---------- K3: final deterministic reduction ----------
__global__ void k_final(const double* __restrict__ partials, int NB, float* __restrict__ out) {
    __shared__ double red[256];
    const int tid = threadIdx.x;
    const int n = NBATCH * NB;
    double s = 0.0;
    for (int i = tid; i < n; i += 256) s += partials[i];
    red[tid] = s;
    __syncthreads();
    for (int st = 128; st > 0; st >>= 1) {
        if (tid < st) red[tid] += red[tid + st];
        __syncthreads();
    }
    if (tid == 0) out[0] = (float)(-red[0] / ((double)NBATCH * NB * NWIN));
}

extern "C" void kernel_launch(void* const* d_in, const int* in_sizes, int n_in,
                              void* d_out, int out_size, void* d_ws, size_t ws_size,
                              hipStream_t stream) {
    const float* pred   = (const float*)d_in[0];
    const float* targ   = (const float*)d_in[1];
    const float* fftmat = (const float*)d_in[3];
    const float* oct    = (const float*)d_in[4];
    const int NB = in_sizes[4] / NROWS;   // 15

    char* ws = (char*)d_ws;
    int*      hdr   = (int*)ws;                          // 1 KB
    ushort_t* wpack = (ushort_t*)(ws + 1024);            // 147456 shorts = 294912 B
    size_t o1 = 1024 + (size_t)KSTEPS * TILES * 2 * 512 * 2;
    size_t xsz = (size_t)NBATCH * NB_MAX * NUMF * 4;
    float*  xbuf = (float*)(ws + o1);
    float*  ybuf = (float*)(ws + o1 + xsz);
    double* partials = (double*)(ws + o1 + 2 * xsz);

    hipLaunchKernelGGL(k_scan, dim3(1), dim3(256), 0, stream, oct, NB, hdr);
    hipLaunchKernelGGL(k_prep, dim3(288), dim3(256), 0, stream, fftmat, wpack);
    hipLaunchKernelGGL(k_stft, dim3(NTX, NBATCH, 2), dim3(768), 0, stream,
                       targ, pred, wpack, hdr, xbuf, ybuf, NB);
    hipLaunchKernelGGL(k_corr, dim3(NB, NBATCH), dim3(256), 0, stream, xbuf, ybuf, NB, partials);
    hipLaunchKernelGGL(k_final, dim3(1), dim3(256), 0, stream, partials, NB, (float*)d_out);
}